// Round 13
// baseline (227.321 us; speedup 1.0000x reference)
//
#include <hip/hip_runtime.h>
#include <hip/hip_bf16.h>
#include <hip/hip_fp16.h>

// Problem constants
#define B_      4
#define N_      2048
#define DIM_    128
#define HEADS_  8
#define HEAD_   128
#define INNER_  1024
#define QKV_    3072
#define EPS_    1e-5f
#define SCALE_  0.08838834764831845f   // HEAD^-0.5
// log2(10000)/64 for rope inv_freq = 2^(-i * this)
#define ROPE_C  0.20762050593046015f

typedef __attribute__((ext_vector_type(8))) short short8;   // 8 bf16 = 4 VGPRs
typedef __attribute__((ext_vector_type(4))) short short4v;  // 4 bf16 = 2 VGPRs
typedef __attribute__((ext_vector_type(4))) float f32x4;    // MFMA C/D

// Workspace (byte offsets, d_ws >= 128 MiB as used in R2/R3):
//  Q     [0,16M)    K [16M,32M)   Vt [32M,48M)     (bf16)
//  qkv   [48M,96M)  bf16 [8192][3072]  -- dead after k_rope
//  Opart [48M,112M) fp32 x2 halves [B][N][INNER]   -- overwrites dead qkv
//  Ob    [0,16M)    bf16, written by k_comb        -- overwrites dead Q
//  xnb   [112M,114M) bf16 [8192][128]
//  wqb   [114M,115M) bf16 [3072][128]
//  wob   [115M,116M) bf16 [128][1024]
//  Spart [116M,116.5M) fp32 [2][32][2048] row sums

__device__ __forceinline__ unsigned short f2bf(float f) {
    unsigned u = __builtin_bit_cast(unsigned, f);
    u = (u + 0x7fffu + ((u >> 16) & 1u)) >> 16;
    return (unsigned short)u;
}
__device__ __forceinline__ float bf2f(unsigned short h) {
    unsigned u = ((unsigned)h) << 16;
    return __builtin_bit_cast(float, u);
}
__device__ __forceinline__ unsigned pk2(float a, float b) {
    return (unsigned)f2bf(a) | ((unsigned)f2bf(b) << 16);
}

// ---------------------------------------------------------------------------
// K0: LayerNorm -> bf16 xnb. One wave per row, lane holds 2 elems.
// ---------------------------------------------------------------------------
__global__ __launch_bounds__(256) void k_ln(
    const float* __restrict__ x, const float* __restrict__ g,
    const float* __restrict__ be, unsigned short* __restrict__ xnb)
{
    const int w = threadIdx.x >> 6, l = threadIdx.x & 63;
    const int row = blockIdx.x * 4 + w;
    float2 v = *(const float2*)(x + (size_t)row * 128 + l * 2);
    float s = v.x + v.y, s2 = v.x * v.x + v.y * v.y;
#pragma unroll
    for (int off = 1; off < 64; off <<= 1) {
        s  += __shfl_xor(s, off);
        s2 += __shfl_xor(s2, off);
    }
    float mu = s * (1.f / 128.f);
    float var = s2 * (1.f / 128.f) - mu * mu;
    float rs = rsqrtf(var + EPS_);
    float2 gg = *(const float2*)(g + l * 2);
    float2 bb = *(const float2*)(be + l * 2);
    float ox = (v.x - mu) * rs * gg.x + bb.x;
    float oy = (v.y - mu) * rs * gg.y + bb.y;
    *(unsigned*)(xnb + (size_t)row * 128 + l * 2) = pk2(ox, oy);
}

// ---------------------------------------------------------------------------
// K0b: fp32 -> bf16 convert (8 elems/thread)
// ---------------------------------------------------------------------------
__global__ __launch_bounds__(256) void k_cvt(
    const float* __restrict__ src, unsigned short* __restrict__ dst)
{
    size_t i = ((size_t)blockIdx.x * 256 + threadIdx.x) * 8;
    float4 f0 = *(const float4*)(src + i), f1 = *(const float4*)(src + i + 4);
    uint4 u = { pk2(f0.x, f0.y), pk2(f0.z, f0.w), pk2(f1.x, f1.y), pk2(f1.z, f1.w) };
    *(uint4*)(dst + i) = u;
}

// ---------------------------------------------------------------------------
// K1: QKV GEMM, bf16-native. M=128 x N=128, K=128 one-shot. Grid (64, 24).
// (R11-validated version -- fused epilogue parked after 2 identical failures)
// ---------------------------------------------------------------------------
__global__ __launch_bounds__(256) void k_qkv_gemm(
    const unsigned short* __restrict__ xnb, const unsigned short* __restrict__ wb,
    unsigned short* __restrict__ qkv)
{
    __shared__ unsigned short lA[128 * 136];
    __shared__ unsigned short lB[128 * 136];
    const int t = threadIdx.x;
    const int wv = t >> 6, l = t & 63;
    const int lm = l & 15, quad = l >> 4;
    const int row0 = blockIdx.x * 128;
    const int e0   = blockIdx.y * 128;

#pragma unroll
    for (int i = 0; i < 8; ++i) {
        int c = t + 256 * i;  int r = c >> 4, c8 = c & 15;
        *(uint4*)&lA[r * 136 + c8 * 8] =
            *(const uint4*)(xnb + (size_t)(row0 + r) * 128 + c8 * 8);
        *(uint4*)&lB[r * 136 + c8 * 8] =
            *(const uint4*)(wb + (size_t)(e0 + r) * 128 + c8 * 8);
    }
    __syncthreads();

    short8 af[2][4];
#pragma unroll
    for (int mt = 0; mt < 2; ++mt)
#pragma unroll
        for (int ks = 0; ks < 4; ++ks)
            af[mt][ks] = *(short8*)&lA[(wv * 32 + mt * 16 + lm) * 136 + ks * 32 + quad * 8];

    f32x4 acc[2][8];
#pragma unroll
    for (int mt = 0; mt < 2; ++mt)
#pragma unroll
        for (int ct = 0; ct < 8; ++ct) acc[mt][ct] = (f32x4){0.f, 0.f, 0.f, 0.f};
#pragma unroll
    for (int ks = 0; ks < 4; ++ks) {
#pragma unroll
        for (int ct = 0; ct < 8; ++ct) {
            short8 b = *(short8*)&lB[(ct * 16 + lm) * 136 + ks * 32 + quad * 8];
            acc[0][ct] = __builtin_amdgcn_mfma_f32_16x16x32_bf16(af[0][ks], b, acc[0][ct], 0, 0, 0);
            acc[1][ct] = __builtin_amdgcn_mfma_f32_16x16x32_bf16(af[1][ks], b, acc[1][ct], 0, 0, 0);
        }
    }
    __syncthreads();

#pragma unroll
    for (int mt = 0; mt < 2; ++mt)
#pragma unroll
        for (int ct = 0; ct < 8; ++ct)
#pragma unroll
            for (int r = 0; r < 4; ++r)
                lA[(wv * 32 + mt * 16 + quad * 4 + r) * 136 + ct * 16 + lm] =
                    f2bf(acc[mt][ct][r]);
    __syncthreads();
#pragma unroll
    for (int i = 0; i < 8; ++i) {
        int c = t + 256 * i;  int r = c >> 4, c8 = c & 15;
        *(uint4*)(qkv + (size_t)(row0 + r) * QKV_ + e0 + c8 * 8) =
            *(uint4*)&lA[r * 136 + c8 * 8];
    }
}

// ---------------------------------------------------------------------------
// K2: rope Q,K (all heads, n < N-1) + scatter; V -> Vt transpose via LDS.
// (R4-validated version, unchanged)
// ---------------------------------------------------------------------------
__global__ __launch_bounds__(256) void k_rope(
    const unsigned short* __restrict__ qkv, unsigned short* __restrict__ Q,
    unsigned short* __restrict__ K, unsigned short* __restrict__ Vt)
{
    __shared__ unsigned lT[128 * 65];
    const int t = threadIdx.x;
    const int bh = blockIdx.x;
    const int n0 = blockIdx.y * 64;
    const int b = bh >> 3, h = bh & 7;
    const int nn = t >> 2, lg = t & 3;
    const int n = n0 + nn;
    const size_t rowb = ((size_t)b * N_ + n) * QKV_;

#pragma unroll
    for (int part = 0; part < 2; ++part) {
        const int coff = part * 1024 + h * 128;
        unsigned short* dst = part == 0 ? Q : K;
#pragma unroll
        for (int jj = 0; jj < 4; ++jj) {
            const int d0 = (lg + jj * 4) * 8;
            short8 vv = *(const short8*)(qkv + rowb + coff + d0);
            unsigned short* pv = (unsigned short*)&vv;
            if (n != N_ - 1) {
#pragma unroll
                for (int p = 0; p < 4; ++p) {
                    int i0 = (d0 >> 1) + p;
                    float invf = exp2f(-(float)i0 * ROPE_C);
                    float th = (float)n * invf;
                    float cs = __cosf(th), sn = __sinf(th);
                    float e = bf2f(pv[2 * p]), o = bf2f(pv[2 * p + 1]);
                    pv[2 * p]     = f2bf(e * cs - o * sn);
                    pv[2 * p + 1] = f2bf(o * cs + e * sn);
                }
            }
            *(short8*)(dst + ((size_t)bh * N_ + n) * HEAD_ + d0) = vv;
        }
    }

#pragma unroll
    for (int jj = 0; jj < 4; ++jj) {
        const int d0 = (lg + jj * 4) * 8;
        short8 vv = *(const short8*)(qkv + rowb + 2048 + h * 128 + d0);
        unsigned short* pv = (unsigned short*)&vv;
#pragma unroll
        for (int j = 0; j < 8; ++j)
            lT[(d0 + j) * 65 + nn] = pv[j];
    }
    __syncthreads();
    {
        const int d = t >> 1, half = t & 1;
        unsigned short ob[32];
#pragma unroll
        for (int i = 0; i < 32; ++i)
            ob[i] = (unsigned short)lT[d * 65 + half * 32 + i];
        unsigned short* dst = Vt + ((size_t)bh * HEAD_ + d) * N_ + n0 + half * 32;
#pragma unroll
        for (int i = 0; i < 4; ++i)
            *(short8*)(dst + i * 8) = *(short8*)&ob[i * 8];
    }
}

// ---------------------------------------------------------------------------
// K3: flash attention, KV-SPLIT. R11 core (S^T form, fixed-shift softmax,
// register prefetch, k-slot-permuted PV) with each block covering HALF the
// key range (16 tiles). Fixed shift => unnormalized partial O's are exactly
// additive across halves. Writes fp32 partials + per-row partial sums.
// Grid 1024 = (ksplit 2) x (qt 16) x (bh 32) -> 4 blocks/CU.
// ---------------------------------------------------------------------------
__global__ __launch_bounds__(256) void k_attn(
    const unsigned short* __restrict__ Q, const unsigned short* __restrict__ K,
    const unsigned short* __restrict__ Vt, float* __restrict__ Opart,
    float* __restrict__ Spart)
{
    __shared__ unsigned short lK[64 * 136];
    __shared__ unsigned short lV[128 * 68];

    const int t = threadIdx.x;
    const int w = t >> 6, l = t & 63;
    const int lm = l & 15, quad = l >> 4;
    const int bid = blockIdx.x;
    const int bh = bid & 31;
    const int rest = bid >> 5;        // 0..31
    const int qt = rest & 15;
    const int ksp = rest >> 4;        // 0 or 1: key half
    const int n0 = qt * 128;
    const int jt0 = ksp * 16;
    const unsigned short* Qb = Q  + (size_t)bh * N_ * HEAD_;
    const unsigned short* Kb = K  + (size_t)bh * N_ * HEAD_;
    const unsigned short* Vb = Vt + (size_t)bh * N_ * HEAD_;

    short8 aq[2][4];
#pragma unroll
    for (int tt = 0; tt < 2; ++tt) {
        const unsigned short* qp =
            Qb + ((size_t)(n0 + tt * 64 + w * 16 + lm)) * 128 + quad * 8;
#pragma unroll
        for (int ks = 0; ks < 4; ++ks)
            aq[tt][ks] = *(const short8*)(qp + ks * 32);
    }

    f32x4 Oa[2][8];
#pragma unroll
    for (int tt = 0; tt < 2; ++tt)
#pragma unroll
        for (int i = 0; i < 8; ++i) Oa[tt][i] = (f32x4){0.f, 0.f, 0.f, 0.f};
    float ps0 = 0.f, ps1 = 0.f;      // per-lane partials for row q = lm
    const float C1 = SCALE_ * 1.44269504f;
    const float C0 = -23.08312f;     // -16*log2(e); const shift is exact

    short8 kr[4], vr[4];
#pragma unroll
    for (int i = 0; i < 4; ++i) {
        int c = t + 256 * i;
        kr[i] = *(const short8*)(Kb + ((size_t)(jt0 * 64 + (c >> 4))) * 128 + (c & 15) * 8);
        vr[i] = *(const short8*)(Vb + (size_t)(c >> 3) * N_ + jt0 * 64 + (c & 7) * 8);
    }

    for (int jt = jt0; jt < jt0 + 16; ++jt) {
        __syncthreads();
#pragma unroll
        for (int i = 0; i < 4; ++i) {
            int c = t + 256 * i;
            *(short8*)&lK[(c >> 4) * 136 + (c & 15) * 8] = kr[i];
            *(short8*)&lV[(c >> 3) * 68  + (c & 7)  * 8] = vr[i];
        }
        __syncthreads();
        if (jt < jt0 + 15) {
#pragma unroll
            for (int i = 0; i < 4; ++i) {
                int c = t + 256 * i;
                kr[i] = *(const short8*)(Kb + ((size_t)((jt + 1) * 64 + (c >> 4))) * 128 + (c & 15) * 8);
                vr[i] = *(const short8*)(Vb + (size_t)(c >> 3) * N_ + (jt + 1) * 64 + (c & 7) * 8);
            }
        }

        short4v pf0[4], pf1[4];
#pragma unroll
        for (int nb = 0; nb < 4; ++nb) {
            f32x4 st0 = (f32x4){0.f, 0.f, 0.f, 0.f};
            f32x4 st1 = (f32x4){0.f, 0.f, 0.f, 0.f};
#pragma unroll
            for (int ks = 0; ks < 4; ++ks) {
                short8 kf = *(short8*)&lK[(nb * 16 + lm) * 136 + ks * 32 + quad * 8];
                st0 = __builtin_amdgcn_mfma_f32_16x16x32_bf16(kf, aq[0][ks], st0, 0, 0, 0);
                st1 = __builtin_amdgcn_mfma_f32_16x16x32_bf16(kf, aq[1][ks], st1, 0, 0, 0);
            }
            unsigned short u0[4], u1[4];
#pragma unroll
            for (int r = 0; r < 4; ++r) {
                float p0 = exp2f(st0[r] * C1 + C0);
                float p1 = exp2f(st1[r] * C1 + C0);
                ps0 += p0;  ps1 += p1;
                u0[r] = f2bf(p0);  u1[r] = f2bf(p1);
            }
            pf0[nb] = *(short4v*)u0;
            pf1[nb] = *(short4v*)u1;
        }

#pragma unroll
        for (int c2 = 0; c2 < 2; ++c2) {
            short8 ap0 = __builtin_shufflevector(pf0[2 * c2], pf0[2 * c2 + 1],
                                                 0, 1, 2, 3, 4, 5, 6, 7);
            short8 ap1 = __builtin_shufflevector(pf1[2 * c2], pf1[2 * c2 + 1],
                                                 0, 1, 2, 3, 4, 5, 6, 7);
#pragma unroll
            for (int nb8 = 0; nb8 < 8; ++nb8) {
                const int rb = (nb8 * 16 + lm) * 68 + c2 * 32 + quad * 4;
                short4v blo = *(short4v*)&lV[rb];
                short4v bhi = *(short4v*)&lV[rb + 16];
                short8 bv = __builtin_shufflevector(blo, bhi, 0, 1, 2, 3, 4, 5, 6, 7);
                Oa[0][nb8] = __builtin_amdgcn_mfma_f32_16x16x32_bf16(ap0, bv, Oa[0][nb8], 0, 0, 0);
                Oa[1][nb8] = __builtin_amdgcn_mfma_f32_16x16x32_bf16(ap1, bv, Oa[1][nb8], 0, 0, 0);
            }
        }
    }

    // full partial row sums in every lane (reduce over quads)
    ps0 += __shfl_xor(ps0, 16);  ps0 += __shfl_xor(ps0, 32);
    ps1 += __shfl_xor(ps1, 16);  ps1 += __shfl_xor(ps1, 32);

    const int b = bh >> 3, h = bh & 7;
    float* Op = Opart + (size_t)ksp * (B_ * N_ * INNER_);
    // store partial sums (lanes of quad 0 hold rows w*16+lm)
    if (quad == 0) {
        Spart[(ksp * 32 + bh) * N_ + n0 + w * 16 + lm]      = ps0;
        Spart[(ksp * 32 + bh) * N_ + n0 + 64 + w * 16 + lm] = ps1;
    }
    // store unnormalized fp32 partial O
#pragma unroll
    for (int tt = 0; tt < 2; ++tt)
#pragma unroll
        for (int r = 0; r < 4; ++r) {
            int n = n0 + tt * 64 + w * 16 + quad * 4 + r;
            float* op = Op + ((size_t)b * N_ + n) * INNER_ + h * HEAD_ + lm;
            f32x4* oa = &Oa[tt][0];
#pragma unroll
            for (int nb8 = 0; nb8 < 8; ++nb8)
                op[nb8 * 16] = oa[nb8][r];
        }
}

// ---------------------------------------------------------------------------
// K3b: combine key-halves: Ob = (O0 + O1) / (s0 + s1), bf16.
// Grid 8192 (one token row), 256 threads (4 floats each).
// ---------------------------------------------------------------------------
__global__ __launch_bounds__(256) void k_comb(
    const float* __restrict__ Opart, const float* __restrict__ Spart,
    unsigned short* __restrict__ Ob)
{
    const int row = blockIdx.x;              // b*2048 + n
    const int b = row >> 11, n = row & 2047;
    const int t = threadIdx.x;
    const int h = t >> 5;                    // 32 threads per head
    const int bh = b * 8 + h;
    float s0 = Spart[(bh) * N_ + n];
    float s1 = Spart[(32 + bh) * N_ + n];
    float inv = 1.f / (s0 + s1);
    const size_t off = (size_t)row * INNER_ + t * 4;
    float4 a = *(const float4*)(Opart + off);
    float4 c = *(const float4*)(Opart + (size_t)(B_ * N_ * INNER_) + off);
    unsigned short p4[4] = { f2bf((a.x + c.x) * inv), f2bf((a.y + c.y) * inv),
                             f2bf((a.z + c.z) * inv), f2bf((a.w + c.w) * inv) };
    *(uint2*)(Ob + off) = *(uint2*)p4;
}

// ---------------------------------------------------------------------------
// K4: output projection, bf16 MFMA. out[8192,128] = Ob @ wob^T + b_out.
// ---------------------------------------------------------------------------
__global__ __launch_bounds__(256) void k_proj(
    const unsigned short* __restrict__ Ob, const unsigned short* __restrict__ wob,
    const float* __restrict__ bias, float* __restrict__ out)
{
    __shared__ unsigned short lA[64 * 136];
    __shared__ unsigned short lB[64 * 136];
    float* lCf = (float*)lA;
    const int t = threadIdx.x;
    const int wv = t >> 6, l = t & 63;
    const int lm = l & 15, quad = l >> 4;
    const int row0 = blockIdx.x * 64;
    const int e0   = blockIdx.y * 64;

    f32x4 acc[4];
#pragma unroll
    for (int ct = 0; ct < 4; ++ct) acc[ct] = (f32x4){0.f, 0.f, 0.f, 0.f};

    for (int kt = 0; kt < 8; ++kt) {
        __syncthreads();
#pragma unroll
        for (int i = 0; i < 4; ++i) {
            int c = t + 256 * i;  int r = c >> 4, c8 = c & 15;
            *(uint4*)&lA[r * 136 + c8 * 8] =
                *(const uint4*)(Ob + (size_t)(row0 + r) * 1024 + kt * 128 + c8 * 8);
            *(uint4*)&lB[r * 136 + c8 * 8] =
                *(const uint4*)(wob + (size_t)(e0 + r) * 1024 + kt * 128 + c8 * 8);
        }
        __syncthreads();
        short8 a_[4];
#pragma unroll
        for (int ks = 0; ks < 4; ++ks)
            a_[ks] = *(short8*)&lA[(wv * 16 + lm) * 136 + ks * 32 + quad * 8];
#pragma unroll
        for (int ks = 0; ks < 4; ++ks)
#pragma unroll
            for (int ct = 0; ct < 4; ++ct) {
                short8 b = *(short8*)&lB[(ct * 16 + lm) * 136 + ks * 32 + quad * 8];
                acc[ct] = __builtin_amdgcn_mfma_f32_16x16x32_bf16(a_[ks], b, acc[ct], 0, 0, 0);
            }
    }
    __syncthreads();
#pragma unroll
    for (int ct = 0; ct < 4; ++ct)
#pragma unroll
        for (int r = 0; r < 4; ++r)
            lCf[(wv * 16 + quad * 4 + r) * 68 + ct * 16 + lm] = acc[ct][r];
    __syncthreads();
#pragma unroll
    for (int i = 0; i < 4; ++i) {
        int c = t + 256 * i;  int r = c >> 4, c4 = c & 15;
        float4 v = *(float4*)&lCf[r * 68 + c4 * 4];
        float4 b4 = *(const float4*)(bias + e0 + c4 * 4);
        v.x += b4.x; v.y += b4.y; v.z += b4.z; v.w += b4.w;
        *(float4*)(out + (size_t)(row0 + r) * 128 + e0 + c4 * 4) = v;
    }
}

// ---------------------------------------------------------------------------
extern "C" void kernel_launch(void* const* d_in, const int* in_sizes, int n_in,
                              void* d_out, int out_size, void* d_ws, size_t ws_size,
                              hipStream_t stream) {
    const float* x      = (const float*)d_in[0];
    const float* gamma  = (const float*)d_in[1];
    const float* beta   = (const float*)d_in[2];
    const float* w_qkv  = (const float*)d_in[3];
    const float* w_out  = (const float*)d_in[4];
    const float* b_out  = (const float*)d_in[5];
    float* out = (float*)d_out;
    char* wsb = (char*)d_ws;
    unsigned short* Q    = (unsigned short*)(wsb);
    unsigned short* K    = (unsigned short*)(wsb + (16ull << 20));
    unsigned short* Vt   = (unsigned short*)(wsb + (32ull << 20));
    unsigned short* qkv  = (unsigned short*)(wsb + (48ull << 20));
    float* Opart         = (float*)(wsb + (48ull << 20));   // overwrites dead qkv
    unsigned short* Ob   = (unsigned short*)(wsb);          // overwrites dead Q
    unsigned short* xnb  = (unsigned short*)(wsb + (112ull << 20));
    unsigned short* wqb  = (unsigned short*)(wsb + (114ull << 20));
    unsigned short* wob  = (unsigned short*)(wsb + (115ull << 20));
    float* Spart         = (float*)(wsb + (116ull << 20));

    k_ln       <<<dim3(2048),    256, 0, stream>>>(x, gamma, beta, xnb);
    k_cvt      <<<dim3(192),     256, 0, stream>>>(w_qkv, wqb);   // 3072*128
    k_cvt      <<<dim3(64),      256, 0, stream>>>(w_out, wob);   // 128*1024
    k_qkv_gemm <<<dim3(64, 24),  256, 0, stream>>>(xnb, wqb, qkv);
    k_rope     <<<dim3(32, 32),  256, 0, stream>>>(qkv, Q, K, Vt);
    k_attn     <<<dim3(1024),    256, 0, stream>>>(Q, K, Vt, Opart, Spart);
    k_comb     <<<dim3(8192),    256, 0, stream>>>(Opart, Spart, Ob);
    k_proj     <<<dim3(128, 2),  256, 0, stream>>>(Ob, wob, b_out, out);
}

// Round 15
// 204.245 us; speedup vs baseline: 1.1130x; 1.1130x over previous
//
#include <hip/hip_runtime.h>
#include <hip/hip_bf16.h>
#include <hip/hip_fp16.h>

// Problem constants
#define B_      4
#define N_      2048
#define DIM_    128
#define HEADS_  8
#define HEAD_   128
#define INNER_  1024
#define QKV_    3072
#define EPS_    1e-5f
#define SCALE_  0.08838834764831845f   // HEAD^-0.5
// log2(10000)/64 for rope inv_freq = 2^(-i * this)
#define ROPE_C  0.20762050593046015f

typedef __attribute__((ext_vector_type(8))) short short8;   // 8 bf16 = 4 VGPRs
typedef __attribute__((ext_vector_type(4))) short short4v;  // 4 bf16 = 2 VGPRs
typedef __attribute__((ext_vector_type(4))) float f32x4;    // MFMA C/D

// Workspace (byte offsets) — R11 layout:
//  Q    [0,16M)   K [16M,32M)   Vt [32M,48M)        (bf16)
//  qkv  [48M,96M) bf16 [8192][3072]  -- dead after k_rope
//  Ob   [48M,64M) bf16 [B][N][INNER] -- written by k_attn after qkv dies
//  xnb  [96M,98M) bf16 [8192][128]
//  wqb  [98M,98.75M) bf16 [3072][128]
//  wob  [99M,99.25M) bf16 [128][1024]

__device__ __forceinline__ unsigned short f2bf(float f) {
    unsigned u = __builtin_bit_cast(unsigned, f);
    u = (u + 0x7fffu + ((u >> 16) & 1u)) >> 16;
    return (unsigned short)u;
}
__device__ __forceinline__ float bf2f(unsigned short h) {
    unsigned u = ((unsigned)h) << 16;
    return __builtin_bit_cast(float, u);
}
__device__ __forceinline__ unsigned pk2(float a, float b) {
    return (unsigned)f2bf(a) | ((unsigned)f2bf(b) << 16);
}
// packed RNE fp32x4 -> bf16x4 via v_cvt_pk_bf16_f32 (HIP API); memcpy for the
// bit move because __hip_bfloat162 is not trivially copyable (R14 lesson).
__device__ __forceinline__ short4v pack4(const float* e) {
    __hip_bfloat162 h0 = __float22bfloat162_rn(make_float2(e[0], e[1]));
    __hip_bfloat162 h1 = __float22bfloat162_rn(make_float2(e[2], e[3]));
    uint2 u;
    __builtin_memcpy(&u.x, &h0, 4);
    __builtin_memcpy(&u.y, &h1, 4);
    return __builtin_bit_cast(short4v, u);
}

// ---------------------------------------------------------------------------
// K0: LayerNorm -> bf16 xnb. One wave per row, lane holds 2 elems.
// ---------------------------------------------------------------------------
__global__ __launch_bounds__(256) void k_ln(
    const float* __restrict__ x, const float* __restrict__ g,
    const float* __restrict__ be, unsigned short* __restrict__ xnb)
{
    const int w = threadIdx.x >> 6, l = threadIdx.x & 63;
    const int row = blockIdx.x * 4 + w;
    float2 v = *(const float2*)(x + (size_t)row * 128 + l * 2);
    float s = v.x + v.y, s2 = v.x * v.x + v.y * v.y;
#pragma unroll
    for (int off = 1; off < 64; off <<= 1) {
        s  += __shfl_xor(s, off);
        s2 += __shfl_xor(s2, off);
    }
    float mu = s * (1.f / 128.f);
    float var = s2 * (1.f / 128.f) - mu * mu;
    float rs = rsqrtf(var + EPS_);
    float2 gg = *(const float2*)(g + l * 2);
    float2 bb = *(const float2*)(be + l * 2);
    float ox = (v.x - mu) * rs * gg.x + bb.x;
    float oy = (v.y - mu) * rs * gg.y + bb.y;
    *(unsigned*)(xnb + (size_t)row * 128 + l * 2) = pk2(ox, oy);
}

// ---------------------------------------------------------------------------
// K0b: fp32 -> bf16 convert (8 elems/thread)
// ---------------------------------------------------------------------------
__global__ __launch_bounds__(256) void k_cvt(
    const float* __restrict__ src, unsigned short* __restrict__ dst)
{
    size_t i = ((size_t)blockIdx.x * 256 + threadIdx.x) * 8;
    float4 f0 = *(const float4*)(src + i), f1 = *(const float4*)(src + i + 4);
    uint4 u = { pk2(f0.x, f0.y), pk2(f0.z, f0.w), pk2(f1.x, f1.y), pk2(f1.z, f1.w) };
    *(uint4*)(dst + i) = u;
}

// ---------------------------------------------------------------------------
// K1: QKV GEMM, bf16-native. M=128 x N=128, K=128 one-shot. Grid (64, 24).
// (R11-validated)
// ---------------------------------------------------------------------------
__global__ __launch_bounds__(256) void k_qkv_gemm(
    const unsigned short* __restrict__ xnb, const unsigned short* __restrict__ wb,
    unsigned short* __restrict__ qkv)
{
    __shared__ unsigned short lA[128 * 136];
    __shared__ unsigned short lB[128 * 136];
    const int t = threadIdx.x;
    const int wv = t >> 6, l = t & 63;
    const int lm = l & 15, quad = l >> 4;
    const int row0 = blockIdx.x * 128;
    const int e0   = blockIdx.y * 128;

#pragma unroll
    for (int i = 0; i < 8; ++i) {
        int c = t + 256 * i;  int r = c >> 4, c8 = c & 15;
        *(uint4*)&lA[r * 136 + c8 * 8] =
            *(const uint4*)(xnb + (size_t)(row0 + r) * 128 + c8 * 8);
        *(uint4*)&lB[r * 136 + c8 * 8] =
            *(const uint4*)(wb + (size_t)(e0 + r) * 128 + c8 * 8);
    }
    __syncthreads();

    short8 af[2][4];
#pragma unroll
    for (int mt = 0; mt < 2; ++mt)
#pragma unroll
        for (int ks = 0; ks < 4; ++ks)
            af[mt][ks] = *(short8*)&lA[(wv * 32 + mt * 16 + lm) * 136 + ks * 32 + quad * 8];

    f32x4 acc[2][8];
#pragma unroll
    for (int mt = 0; mt < 2; ++mt)
#pragma unroll
        for (int ct = 0; ct < 8; ++ct) acc[mt][ct] = (f32x4){0.f, 0.f, 0.f, 0.f};
#pragma unroll
    for (int ks = 0; ks < 4; ++ks) {
#pragma unroll
        for (int ct = 0; ct < 8; ++ct) {
            short8 b = *(short8*)&lB[(ct * 16 + lm) * 136 + ks * 32 + quad * 8];
            acc[0][ct] = __builtin_amdgcn_mfma_f32_16x16x32_bf16(af[0][ks], b, acc[0][ct], 0, 0, 0);
            acc[1][ct] = __builtin_amdgcn_mfma_f32_16x16x32_bf16(af[1][ks], b, acc[1][ct], 0, 0, 0);
        }
    }
    __syncthreads();

#pragma unroll
    for (int mt = 0; mt < 2; ++mt)
#pragma unroll
        for (int ct = 0; ct < 8; ++ct)
#pragma unroll
            for (int r = 0; r < 4; ++r)
                lA[(wv * 32 + mt * 16 + quad * 4 + r) * 136 + ct * 16 + lm] =
                    f2bf(acc[mt][ct][r]);
    __syncthreads();
#pragma unroll
    for (int i = 0; i < 8; ++i) {
        int c = t + 256 * i;  int r = c >> 4, c8 = c & 15;
        *(uint4*)(qkv + (size_t)(row0 + r) * QKV_ + e0 + c8 * 8) =
            *(uint4*)&lA[r * 136 + c8 * 8];
    }
}

// ---------------------------------------------------------------------------
// K2: rope Q,K (all heads, n < N-1) + scatter; V -> Vt transpose via LDS.
// (R4-validated, unchanged)
// ---------------------------------------------------------------------------
__global__ __launch_bounds__(256) void k_rope(
    const unsigned short* __restrict__ qkv, unsigned short* __restrict__ Q,
    unsigned short* __restrict__ K, unsigned short* __restrict__ Vt)
{
    __shared__ unsigned lT[128 * 65];
    const int t = threadIdx.x;
    const int bh = blockIdx.x;
    const int n0 = blockIdx.y * 64;
    const int b = bh >> 3, h = bh & 7;
    const int nn = t >> 2, lg = t & 3;
    const int n = n0 + nn;
    const size_t rowb = ((size_t)b * N_ + n) * QKV_;

#pragma unroll
    for (int part = 0; part < 2; ++part) {
        const int coff = part * 1024 + h * 128;
        unsigned short* dst = part == 0 ? Q : K;
#pragma unroll
        for (int jj = 0; jj < 4; ++jj) {
            const int d0 = (lg + jj * 4) * 8;
            short8 vv = *(const short8*)(qkv + rowb + coff + d0);
            unsigned short* pv = (unsigned short*)&vv;
            if (n != N_ - 1) {
#pragma unroll
                for (int p = 0; p < 4; ++p) {
                    int i0 = (d0 >> 1) + p;
                    float invf = exp2f(-(float)i0 * ROPE_C);
                    float th = (float)n * invf;
                    float cs = __cosf(th), sn = __sinf(th);
                    float e = bf2f(pv[2 * p]), o = bf2f(pv[2 * p + 1]);
                    pv[2 * p]     = f2bf(e * cs - o * sn);
                    pv[2 * p + 1] = f2bf(o * cs + e * sn);
                }
            }
            *(short8*)(dst + ((size_t)bh * N_ + n) * HEAD_ + d0) = vv;
        }
    }

#pragma unroll
    for (int jj = 0; jj < 4; ++jj) {
        const int d0 = (lg + jj * 4) * 8;
        short8 vv = *(const short8*)(qkv + rowb + 2048 + h * 128 + d0);
        unsigned short* pv = (unsigned short*)&vv;
#pragma unroll
        for (int j = 0; j < 8; ++j)
            lT[(d0 + j) * 65 + nn] = pv[j];
    }
    __syncthreads();
    {
        const int d = t >> 1, half = t & 1;
        unsigned short ob[32];
#pragma unroll
        for (int i = 0; i < 32; ++i)
            ob[i] = (unsigned short)lT[d * 65 + half * 32 + i];
        unsigned short* dst = Vt + ((size_t)bh * HEAD_ + d) * N_ + n0 + half * 32;
#pragma unroll
        for (int i = 0; i < 4; ++i)
            *(short8*)(dst + i * 8) = *(short8*)&ob[i * 8];
    }
}

// ---------------------------------------------------------------------------
// K3: flash attention (R11 core). Single change vs R11: P packing uses
// v_cvt_pk_bf16_f32 (via __float22bfloat162_rn) instead of 3-op manual RNE —
// same rounding, ~1/4 the VALU ops in the hot loop.
// ---------------------------------------------------------------------------
__global__ __launch_bounds__(256) void k_attn(
    const unsigned short* __restrict__ Q, const unsigned short* __restrict__ K,
    const unsigned short* __restrict__ Vt, unsigned short* __restrict__ Ob)
{
    __shared__ unsigned short lK[64 * 136];
    __shared__ unsigned short lV[128 * 68];

    const int t = threadIdx.x;
    const int w = t >> 6, l = t & 63;
    const int lm = l & 15, quad = l >> 4;
    const int bid = blockIdx.x;
    const int bh = bid & 31;
    const int qt = bid >> 5;          // 0..15
    const int n0 = qt * 128;
    const unsigned short* Qb = Q  + (size_t)bh * N_ * HEAD_;
    const unsigned short* Kb = K  + (size_t)bh * N_ * HEAD_;
    const unsigned short* Vb = Vt + (size_t)bh * N_ * HEAD_;

    short8 aq[2][4];
#pragma unroll
    for (int tt = 0; tt < 2; ++tt) {
        const unsigned short* qp =
            Qb + ((size_t)(n0 + tt * 64 + w * 16 + lm)) * 128 + quad * 8;
#pragma unroll
        for (int ks = 0; ks < 4; ++ks)
            aq[tt][ks] = *(const short8*)(qp + ks * 32);
    }

    f32x4 Oa[2][8];
#pragma unroll
    for (int tt = 0; tt < 2; ++tt)
#pragma unroll
        for (int i = 0; i < 8; ++i) Oa[tt][i] = (f32x4){0.f, 0.f, 0.f, 0.f};
    float ps0 = 0.f, ps1 = 0.f;      // per-lane partials for row q = lm
    const float C1 = SCALE_ * 1.44269504f;
    const float C0 = -23.08312f;     // -16*log2(e); const shift is exact

    short8 kr[4], vr[4];
#pragma unroll
    for (int i = 0; i < 4; ++i) {
        int c = t + 256 * i;
        kr[i] = *(const short8*)(Kb + ((size_t)(c >> 4)) * 128 + (c & 15) * 8);
        vr[i] = *(const short8*)(Vb + (size_t)(c >> 3) * N_ + (c & 7) * 8);
    }

    for (int jt = 0; jt < 32; ++jt) {
        __syncthreads();
#pragma unroll
        for (int i = 0; i < 4; ++i) {
            int c = t + 256 * i;
            *(short8*)&lK[(c >> 4) * 136 + (c & 15) * 8] = kr[i];
            *(short8*)&lV[(c >> 3) * 68  + (c & 7)  * 8] = vr[i];
        }
        __syncthreads();
        if (jt < 31) {
#pragma unroll
            for (int i = 0; i < 4; ++i) {
                int c = t + 256 * i;
                kr[i] = *(const short8*)(Kb + ((size_t)((jt + 1) * 64 + (c >> 4))) * 128 + (c & 15) * 8);
                vr[i] = *(const short8*)(Vb + (size_t)(c >> 3) * N_ + (jt + 1) * 64 + (c & 7) * 8);
            }
        }

        short4v pf0[4], pf1[4];
#pragma unroll
        for (int nb = 0; nb < 4; ++nb) {
            f32x4 st0 = (f32x4){0.f, 0.f, 0.f, 0.f};
            f32x4 st1 = (f32x4){0.f, 0.f, 0.f, 0.f};
#pragma unroll
            for (int ks = 0; ks < 4; ++ks) {
                short8 kf = *(short8*)&lK[(nb * 16 + lm) * 136 + ks * 32 + quad * 8];
                st0 = __builtin_amdgcn_mfma_f32_16x16x32_bf16(kf, aq[0][ks], st0, 0, 0, 0);
                st1 = __builtin_amdgcn_mfma_f32_16x16x32_bf16(kf, aq[1][ks], st1, 0, 0, 0);
            }
            float e0[4], e1[4];
#pragma unroll
            for (int r = 0; r < 4; ++r) {
                e0[r] = exp2f(st0[r] * C1 + C0);
                e1[r] = exp2f(st1[r] * C1 + C0);
                ps0 += e0[r];  ps1 += e1[r];
            }
            pf0[nb] = pack4(e0);
            pf1[nb] = pack4(e1);
        }

#pragma unroll
        for (int c2 = 0; c2 < 2; ++c2) {
            short8 ap0 = __builtin_shufflevector(pf0[2 * c2], pf0[2 * c2 + 1],
                                                 0, 1, 2, 3, 4, 5, 6, 7);
            short8 ap1 = __builtin_shufflevector(pf1[2 * c2], pf1[2 * c2 + 1],
                                                 0, 1, 2, 3, 4, 5, 6, 7);
#pragma unroll
            for (int nb8 = 0; nb8 < 8; ++nb8) {
                const int rb = (nb8 * 16 + lm) * 68 + c2 * 32 + quad * 4;
                short4v blo = *(short4v*)&lV[rb];
                short4v bhi = *(short4v*)&lV[rb + 16];
                short8 bv = __builtin_shufflevector(blo, bhi, 0, 1, 2, 3, 4, 5, 6, 7);
                Oa[0][nb8] = __builtin_amdgcn_mfma_f32_16x16x32_bf16(ap0, bv, Oa[0][nb8], 0, 0, 0);
                Oa[1][nb8] = __builtin_amdgcn_mfma_f32_16x16x32_bf16(ap1, bv, Oa[1][nb8], 0, 0, 0);
            }
        }
    }

    ps0 += __shfl_xor(ps0, 16);  ps0 += __shfl_xor(ps0, 32);
    ps1 += __shfl_xor(ps1, 16);  ps1 += __shfl_xor(ps1, 32);

    const int b = bh >> 3, h = bh & 7;
#pragma unroll
    for (int tt = 0; tt < 2; ++tt)
#pragma unroll
        for (int r = 0; r < 4; ++r) {
            float lsum = __shfl(tt == 0 ? ps0 : ps1, (l & 48) | (quad * 4 + r));
            float il = 1.f / lsum;
            int n = n0 + tt * 64 + w * 16 + quad * 4 + r;
            unsigned short* op = Ob + ((size_t)b * N_ + n) * INNER_ + h * HEAD_ + lm;
#pragma unroll
            for (int nb8 = 0; nb8 < 8; ++nb8)
                op[nb8 * 16] = f2bf(Oa[tt][nb8][r] * il);
        }
}

// ---------------------------------------------------------------------------
// K4: output projection, bf16 MFMA. out[8192,128] = Ob @ wob^T + b_out.
// ---------------------------------------------------------------------------
__global__ __launch_bounds__(256) void k_proj(
    const unsigned short* __restrict__ Ob, const unsigned short* __restrict__ wob,
    const float* __restrict__ bias, float* __restrict__ out)
{
    __shared__ unsigned short lA[64 * 136];
    __shared__ unsigned short lB[64 * 136];
    float* lCf = (float*)lA;
    const int t = threadIdx.x;
    const int wv = t >> 6, l = t & 63;
    const int lm = l & 15, quad = l >> 4;
    const int row0 = blockIdx.x * 64;
    const int e0   = blockIdx.y * 64;

    f32x4 acc[4];
#pragma unroll
    for (int ct = 0; ct < 4; ++ct) acc[ct] = (f32x4){0.f, 0.f, 0.f, 0.f};

    for (int kt = 0; kt < 8; ++kt) {
        __syncthreads();
#pragma unroll
        for (int i = 0; i < 4; ++i) {
            int c = t + 256 * i;  int r = c >> 4, c8 = c & 15;
            *(uint4*)&lA[r * 136 + c8 * 8] =
                *(const uint4*)(Ob + (size_t)(row0 + r) * 1024 + kt * 128 + c8 * 8);
            *(uint4*)&lB[r * 136 + c8 * 8] =
                *(const uint4*)(wob + (size_t)(e0 + r) * 1024 + kt * 128 + c8 * 8);
        }
        __syncthreads();
        short8 a_[4];
#pragma unroll
        for (int ks = 0; ks < 4; ++ks)
            a_[ks] = *(short8*)&lA[(wv * 16 + lm) * 136 + ks * 32 + quad * 8];
#pragma unroll
        for (int ks = 0; ks < 4; ++ks)
#pragma unroll
            for (int ct = 0; ct < 4; ++ct) {
                short8 b = *(short8*)&lB[(ct * 16 + lm) * 136 + ks * 32 + quad * 8];
                acc[ct] = __builtin_amdgcn_mfma_f32_16x16x32_bf16(a_[ks], b, acc[ct], 0, 0, 0);
            }
    }
    __syncthreads();
#pragma unroll
    for (int ct = 0; ct < 4; ++ct)
#pragma unroll
        for (int r = 0; r < 4; ++r)
            lCf[(wv * 16 + quad * 4 + r) * 68 + ct * 16 + lm] = acc[ct][r];
    __syncthreads();
#pragma unroll
    for (int i = 0; i < 4; ++i) {
        int c = t + 256 * i;  int r = c >> 4, c4 = c & 15;
        float4 v = *(float4*)&lCf[r * 68 + c4 * 4];
        float4 b4 = *(const float4*)(bias + e0 + c4 * 4);
        v.x += b4.x; v.y += b4.y; v.z += b4.z; v.w += b4.w;
        *(float4*)(out + (size_t)(row0 + r) * 128 + e0 + c4 * 4) = v;
    }
}

// ---------------------------------------------------------------------------
extern "C" void kernel_launch(void* const* d_in, const int* in_sizes, int n_in,
                              void* d_out, int out_size, void* d_ws, size_t ws_size,
                              hipStream_t stream) {
    const float* x      = (const float*)d_in[0];
    const float* gamma  = (const float*)d_in[1];
    const float* beta   = (const float*)d_in[2];
    const float* w_qkv  = (const float*)d_in[3];
    const float* w_out  = (const float*)d_in[4];
    const float* b_out  = (const float*)d_in[5];
    float* out = (float*)d_out;
    char* wsb = (char*)d_ws;
    unsigned short* Q    = (unsigned short*)(wsb);
    unsigned short* K    = (unsigned short*)(wsb + (16ull << 20));
    unsigned short* Vt   = (unsigned short*)(wsb + (32ull << 20));
    unsigned short* qkv  = (unsigned short*)(wsb + (48ull << 20));
    unsigned short* Ob   = (unsigned short*)(wsb + (48ull << 20));  // after qkv dies
    unsigned short* xnb  = (unsigned short*)(wsb + (96ull << 20));
    unsigned short* wqb  = (unsigned short*)(wsb + (98ull << 20));
    unsigned short* wob  = (unsigned short*)(wsb + (99ull << 20));

    k_ln       <<<dim3(2048),    256, 0, stream>>>(x, gamma, beta, xnb);
    k_cvt      <<<dim3(192),     256, 0, stream>>>(w_qkv, wqb);   // 3072*128
    k_cvt      <<<dim3(64),      256, 0, stream>>>(w_out, wob);   // 128*1024
    k_qkv_gemm <<<dim3(64, 24),  256, 0, stream>>>(xnb, wqb, qkv);
    k_rope     <<<dim3(32, 32),  256, 0, stream>>>(qkv, Q, K, Vt);
    k_attn     <<<dim3(512),     256, 0, stream>>>(Q, K, Vt, Ob);
    k_proj     <<<dim3(128, 2),  256, 0, stream>>>(Ob, wob, b_out, out);
}